// Round 12
// baseline (44.009 us; speedup 1.0000x reference)
//
#include <hip/hip_runtime.h>

// Problem: B=4, N=384, DX=2, DR=128, H=128, DOUT=64
// out[b,n,m,o] = relu( (x_ctx[b,n]-x_ctx[b,m]) @ W1[0:2] + r[b] @ W1[2:130] + b1 ) @ W2 + b2
//
// Round-12: R11 with 2 blocks/CU (grid 512, 3 rows/block; 384%3==0 so a
// block's rows never span a batch).
// Model validated by R11: store-path BW is set by outstanding store bytes
// (Little's law). R11 = 4 waves/CU x ~4KB = ~16KB outstanding -> 16/23 x
// 6.6 = 4.6 TB/s -> predicted 33us, observed 32.9us. Doubling the
// store-issuing waves to 8/CU gives ~32KB > ~23KB needed for ~6.6 TB/s;
// block 2's main loop also overlaps block 1's prologue.
// Kept from R4/R11 (evidence): per-wave LDS transpose -> 4x1KB contiguous
// cached stores (R6 strided=3.0TB/s, R7 NT=2.1TB/s, R8 asm=RFO blowup),
// no inline asm, single barrier, prologue amortized over rows.

typedef __attribute__((ext_vector_type(8))) __bf16 bf16x8;
typedef __attribute__((ext_vector_type(4))) float f32x4;

#define B_    4
#define N_    384
#define H_    128
#define DOUT_ 64
#define ROWS_ 3

__global__ __launch_bounds__(256, 2) void te_fused(
    const float* __restrict__ r, const float* __restrict__ xctx,
    const float* __restrict__ W1, const float* __restrict__ b1,
    const float* __restrict__ W2, const float* __restrict__ b2,
    float* __restrict__ out)
{
    __shared__ __align__(16) float xs[N_ * 2];        // 3 KB  x_ctx[b]
    __shared__ __align__(16) float cpart[2][H_];      // 1 KB  c partials
    __shared__ __align__(16) float tbuf[4][16][64];   // 16 KB per-wave transpose

    const int tid  = threadIdx.x;
    const int wave = tid >> 6, lane = tid & 63;
    const int g = lane >> 4, rl = lane & 15;

    const int bid  = blockIdx.x;          // 0..511
    const int row0 = bid * ROWS_;         // first global row; rows share b
    const int b    = row0 / N_;
    const int n0   = row0 - b * N_;

    // ---- prologue: c partial reduction (all 256 threads) ----
    {
        const int k = tid & 127, dh = tid >> 7;
        float acc = dh ? 0.f : b1[k];
        const float* wc = W1 + (2 + dh * 64) * H_ + k;
        const float* rb = r + b * 128 + dh * 64;
        #pragma unroll 8
        for (int d = 0; d < 64; ++d) acc = fmaf(rb[d], wc[d * H_], acc);
        cpart[dh][k] = acc;
    }
    // ---- stage x_ctx[b] (192 threads x 16 B) ----
    if (tid < 192)
        *reinterpret_cast<f32x4*>(&xs[tid * 4]) =
            *reinterpret_cast<const f32x4*>(xctx + b * (N_ * 2) + tid * 4);

    // ---- W2^T fragments: w2f[rt][ks][jj] = bf16(W2[kk][rt*16+rl]),
    //      kk = ks*32 + (jj>=4)*16 + g*4 + (jj&3)  (scalar gathers, L2-hit) ----
    bf16x8 w2f[4][4];
    #pragma unroll
    for (int rt = 0; rt < 4; ++rt) {
        const float* wp = W2 + rt * 16 + rl;   // + kk*64
        #pragma unroll
        for (int ks = 0; ks < 4; ++ks)
            #pragma unroll
            for (int jj = 0; jj < 8; ++jj) {
                const int kk = ks * 32 + ((jj >> 2) << 4) + (g << 2) + (jj & 3);
                w2f[rt][ks][jj] = (__bf16)wp[kk * DOUT_];
            }
    }

    // ---- W1 row-0/row-1 fragments + b2 fragments ----
    f32x4 w1a[4][2], w1b[4][2], cf[4][2], b2f[4];
    #pragma unroll
    for (int ks = 0; ks < 4; ++ks)
        #pragma unroll
        for (int hh = 0; hh < 2; ++hh) {
            const int kk = ks * 32 + hh * 16 + (g << 2);
            w1a[ks][hh] = *reinterpret_cast<const f32x4*>(W1 + kk);
            w1b[ks][hh] = *reinterpret_cast<const f32x4*>(W1 + H_ + kk);
        }
    #pragma unroll
    for (int rt = 0; rt < 4; ++rt)
        b2f[rt] = *reinterpret_cast<const f32x4*>(b2 + rt * 16 + (g << 2));

    __syncthreads();   // xs + cpart ready (only barrier in the kernel)

    // ---- c fragments ----
    #pragma unroll
    for (int ks = 0; ks < 4; ++ks)
        #pragma unroll
        for (int hh = 0; hh < 2; ++hh) {
            const int kk = ks * 32 + hh * 16 + (g << 2);
            cf[ks][hh] = *reinterpret_cast<const f32x4*>(&cpart[0][kk]) +
                         *reinterpret_cast<const f32x4*>(&cpart[1][kk]);
        }

    float* tb = &tbuf[wave][0][0];
    const int cb2 = lane & 15;

    // ---- ROWS_ rows x 6 m-tiles; store pattern identical to R4/R11 ----
    for (int rr = 0; rr < ROWS_; ++rr) {
        const int n = n0 + rr;
        const float x0n = xs[2 * n], x1n = xs[2 * n + 1];
        float* const outn = out + ((size_t)(row0 + rr)) * N_ * DOUT_;

        for (int t = 0; t < 6; ++t) {
            const int mbase = wave * 96 + t * 16;
            const int m = mbase + rl;
            const float dx0 = x0n - xs[2 * m];
            const float dx1 = x1n - xs[2 * m + 1];

            bf16x8 hf[4];
            #pragma unroll
            for (int ks = 0; ks < 4; ++ks)
                #pragma unroll
                for (int hh = 0; hh < 2; ++hh)
                    #pragma unroll
                    for (int j = 0; j < 4; ++j) {
                        float hp = fmaf(dx1, w1b[ks][hh][j],
                                   fmaf(dx0, w1a[ks][hh][j], cf[ks][hh][j]));
                        hf[ks][hh * 4 + j] = (__bf16)(hp > 0.f ? hp : 0.f);
                    }

            f32x4 acc[4];
            #pragma unroll
            for (int rt = 0; rt < 4; ++rt) acc[rt] = b2f[rt];
            #pragma unroll
            for (int ks = 0; ks < 4; ++ks)
                #pragma unroll
                for (int rt = 0; rt < 4; ++rt)
                    acc[rt] = __builtin_amdgcn_mfma_f32_16x16x32_bf16(w2f[rt][ks], hf[ks], acc[rt], 0, 0, 0);

            // per-wave LDS transpose (XOR block swizzle) -> 4 x 1KB contiguous stores
            #pragma unroll
            for (int rt = 0; rt < 4; ++rt) {
                const int cblk = ((rt << 2) | g) ^ rl;
                *reinterpret_cast<f32x4*>(tb + (rl << 6) + (cblk << 2)) = acc[rt];
            }
            float* onp = outn + (size_t)mbase * DOUT_;
            #pragma unroll
            for (int q = 0; q < 4; ++q) {
                const int mm = (lane >> 4) | (q << 2);
                f32x4 rowv = *reinterpret_cast<const f32x4*>(tb + (mm << 6) + ((cb2 ^ mm) << 2));
                *reinterpret_cast<f32x4*>(onp + mm * DOUT_ + (cb2 << 2)) = rowv;
            }
        }
    }
}

extern "C" void kernel_launch(void* const* d_in, const int* in_sizes, int n_in,
                              void* d_out, int out_size, void* d_ws, size_t ws_size,
                              hipStream_t stream)
{
    const float* r    = (const float*)d_in[0];
    const float* xctx = (const float*)d_in[1];
    // d_in[2] = y_ctx (unused), d_in[3] = x_trg (unused)
    const float* W1 = (const float*)d_in[4];
    const float* b1 = (const float*)d_in[5];
    const float* W2 = (const float*)d_in[6];
    const float* b2 = (const float*)d_in[7];
    float* out = (float*)d_out;

    hipLaunchKernelGGL(te_fused, dim3((B_ * N_) / ROWS_), dim3(256), 0, stream,
                       r, xctx, W1, b1, W2, b2, out);
}

// Round 13
// 33.395 us; speedup vs baseline: 1.3178x; 1.3178x over previous
//
#include <hip/hip_runtime.h>

// Problem: B=4, N=384, DX=2, DR=128, H=128, DOUT=64
// out[b,n,m,o] = relu( (x_ctx[b,n]-x_ctx[b,m]) @ W1[0:2] + r[b] @ W1[2:130] + b1 ) @ W2 + b2
//
// Round-13: R11 (grid 256, 1 block/CU, 6 rows/block, 4 waves -- best 32.9us)
// + R10's 3-BANK pipelined epilogue across the flat 36-tile sequence.
// Why: R12 falsified "more outstanding bytes" (8 waves/CU = 44us WORSE than
// 4 waves = 32.9; fillBuffer does 6.7 TB/s at ~3 waves/CU). fillBuffer never
// redefines its store-data register -> no WAR stall. Our loop redefines
// rowv every ~700cy < store latency (~1500cy) -> wave stalls; with only
// 1 wave/SIMD there is nothing to hide the stall. R10's banked test was
// confounded (8 waves/CU + 3 generations = contention regime). Here banks
// rotate over 3 tiles -> a bank's registers are redefined ~2100cy after its
// stores issue -> WAR satisfied on arrival.
// Kept (evidence): per-wave LDS transpose -> 4x1KB contiguous cached stores
// (R6 strided=3.0, R7 NT=2.1, R8 asm/scalarized=1.4 TB/s + RFO), no inline
// asm, single barrier, 4 writer-waves/CU (R12: 8 waves regressed).

typedef __attribute__((ext_vector_type(8))) __bf16 bf16x8;
typedef __attribute__((ext_vector_type(4))) float f32x4;

#define B_    4
#define N_    384
#define H_    128
#define DOUT_ 64

__global__ __launch_bounds__(256, 1) void te_fused(
    const float* __restrict__ r, const float* __restrict__ xctx,
    const float* __restrict__ W1, const float* __restrict__ b1,
    const float* __restrict__ W2, const float* __restrict__ b2,
    float* __restrict__ out)
{
    __shared__ __align__(16) float xs[N_ * 2];        // 3 KB  x_ctx[b]
    __shared__ __align__(16) float cpart[2][H_];      // 1 KB  c partials
    __shared__ __align__(16) float tbuf[4][16][64];   // 16 KB per-wave transpose

    const int tid  = threadIdx.x;
    const int wave = tid >> 6, lane = tid & 63;
    const int g = lane >> 4, rl = lane & 15;

    const int bid  = blockIdx.x;       // 0..255
    const int row0 = bid * 6;          // first global row; all 6 share b
    const int b    = row0 / N_;
    const int n0   = row0 - b * N_;

    // ---- prologue: c partial reduction (all 256 threads) ----
    {
        const int k = tid & 127, dh = tid >> 7;
        float acc = dh ? 0.f : b1[k];
        const float* wc = W1 + (2 + dh * 64) * H_ + k;
        const float* rb = r + b * 128 + dh * 64;
        #pragma unroll 8
        for (int d = 0; d < 64; ++d) acc = fmaf(rb[d], wc[d * H_], acc);
        cpart[dh][k] = acc;
    }
    // ---- stage x_ctx[b] (192 threads x 16 B) ----
    if (tid < 192)
        *reinterpret_cast<f32x4*>(&xs[tid * 4]) =
            *reinterpret_cast<const f32x4*>(xctx + b * (N_ * 2) + tid * 4);

    // ---- W2^T fragments: w2f[rt][ks][jj] = bf16(W2[kk][rt*16+rl]),
    //      kk = ks*32 + (jj>=4)*16 + g*4 + (jj&3)  (scalar gathers, L2-hit) ----
    bf16x8 w2f[4][4];
    #pragma unroll
    for (int rt = 0; rt < 4; ++rt) {
        const float* wp = W2 + rt * 16 + rl;   // + kk*64
        #pragma unroll
        for (int ks = 0; ks < 4; ++ks)
            #pragma unroll
            for (int jj = 0; jj < 8; ++jj) {
                const int kk = ks * 32 + ((jj >> 2) << 4) + (g << 2) + (jj & 3);
                w2f[rt][ks][jj] = (__bf16)wp[kk * DOUT_];
            }
    }

    // ---- W1 row-0/row-1 fragments + b2 fragments ----
    f32x4 w1a[4][2], w1b[4][2], cf[4][2], b2f[4];
    #pragma unroll
    for (int ks = 0; ks < 4; ++ks)
        #pragma unroll
        for (int hh = 0; hh < 2; ++hh) {
            const int kk = ks * 32 + hh * 16 + (g << 2);
            w1a[ks][hh] = *reinterpret_cast<const f32x4*>(W1 + kk);
            w1b[ks][hh] = *reinterpret_cast<const f32x4*>(W1 + H_ + kk);
        }
    #pragma unroll
    for (int rt = 0; rt < 4; ++rt)
        b2f[rt] = *reinterpret_cast<const f32x4*>(b2 + rt * 16 + (g << 2));

    __syncthreads();   // xs + cpart ready (only barrier in the kernel)

    // ---- c fragments ----
    #pragma unroll
    for (int ks = 0; ks < 4; ++ks)
        #pragma unroll
        for (int hh = 0; hh < 2; ++hh) {
            const int kk = ks * 32 + hh * 16 + (g << 2);
            cf[ks][hh] = *reinterpret_cast<const f32x4*>(&cpart[0][kk]) +
                         *reinterpret_cast<const f32x4*>(&cpart[1][kk]);
        }

    float* tb = &tbuf[wave][0][0];
    const int cb2 = lane & 15;
    float* const outb0 = out + (size_t)row0 * N_ * DOUT_;

    // ---- flat tile index i = rr*6 + t over 36 tiles ----
    // compute tile i: h-preact, 16 MFMA, LDS transpose, readback into bank;
    // record the tile's store base pointer in p.
    auto compute_tile = [&](int i, f32x4* bank, float*& p) {
        const int rr = i / 6, t = i - rr * 6;
        const int n  = n0 + rr;
        const float x0n = xs[2 * n], x1n = xs[2 * n + 1];
        const int mbase = wave * 96 + t * 16;
        const int m = mbase + rl;
        const float dx0 = x0n - xs[2 * m];
        const float dx1 = x1n - xs[2 * m + 1];

        bf16x8 hf[4];
        #pragma unroll
        for (int ks = 0; ks < 4; ++ks)
            #pragma unroll
            for (int hh = 0; hh < 2; ++hh)
                #pragma unroll
                for (int j = 0; j < 4; ++j) {
                    float hp = fmaf(dx1, w1b[ks][hh][j],
                               fmaf(dx0, w1a[ks][hh][j], cf[ks][hh][j]));
                    hf[ks][hh * 4 + j] = (__bf16)(hp > 0.f ? hp : 0.f);
                }

        f32x4 acc[4];
        #pragma unroll
        for (int rt = 0; rt < 4; ++rt) acc[rt] = b2f[rt];
        #pragma unroll
        for (int ks = 0; ks < 4; ++ks)
            #pragma unroll
            for (int rt = 0; rt < 4; ++rt)
                acc[rt] = __builtin_amdgcn_mfma_f32_16x16x32_bf16(w2f[rt][ks], hf[ks], acc[rt], 0, 0, 0);

        // per-wave LDS transpose (XOR block swizzle, bank-uniform); same-wave
        // in-order DS pipe makes write->read safe without a barrier.
        #pragma unroll
        for (int rt = 0; rt < 4; ++rt) {
            const int cblk = ((rt << 2) | g) ^ rl;
            *reinterpret_cast<f32x4*>(tb + (rl << 6) + (cblk << 2)) = acc[rt];
        }
        #pragma unroll
        for (int q = 0; q < 4; ++q) {
            const int mm = (lane >> 4) | (q << 2);
            bank[q] = *reinterpret_cast<const f32x4*>(tb + (mm << 6) + ((cb2 ^ mm) << 2));
        }
        p = outb0 + ((size_t)rr * N_ + mbase) * DOUT_;
    };

    // store tile from bank: 4 x 1KB fully-contiguous cached stores
    auto store_tile = [&](float* p, const f32x4* bank) {
        #pragma unroll
        for (int q = 0; q < 4; ++q) {
            const int mm = (lane >> 4) | (q << 2);
            *reinterpret_cast<f32x4*>(p + mm * DOUT_ + (cb2 << 2)) = bank[q];
        }
    };

    // 3-bank rotation over 36 tiles: store(i-1) issues before compute(i);
    // a bank's registers are redefined ~2 tiles (~2100cy) after its stores.
    f32x4 rv0[4], rv1[4], rv2[4];
    float *p0, *p1, *p2;
    compute_tile(0, rv0, p0);
    for (int grp = 0; grp < 11; ++grp) {
        const int base = grp * 3;      // handles tiles base+1 .. base+3
        store_tile(p0, rv0);  compute_tile(base + 1, rv1, p1);
        store_tile(p1, rv1);  compute_tile(base + 2, rv2, p2);
        store_tile(p2, rv2);  compute_tile(base + 3, rv0, p0);
    }
    store_tile(p0, rv0);  compute_tile(34, rv1, p1);
    store_tile(p1, rv1);  compute_tile(35, rv2, p2);
    store_tile(p2, rv2);
}

extern "C" void kernel_launch(void* const* d_in, const int* in_sizes, int n_in,
                              void* d_out, int out_size, void* d_ws, size_t ws_size,
                              hipStream_t stream)
{
    const float* r    = (const float*)d_in[0];
    const float* xctx = (const float*)d_in[1];
    // d_in[2] = y_ctx (unused), d_in[3] = x_trg (unused)
    const float* W1 = (const float*)d_in[4];
    const float* b1 = (const float*)d_in[5];
    const float* W2 = (const float*)d_in[6];
    const float* b2 = (const float*)d_in[7];
    float* out = (float*)d_out;

    hipLaunchKernelGGL(te_fused, dim3(256), dim3(256), 0, stream,
                       r, xctx, W1, b1, W2, b2, out);
}

// Round 14
// 33.071 us; speedup vs baseline: 1.3307x; 1.0098x over previous
//
#include <hip/hip_runtime.h>

// Problem: B=4, N=384, DX=2, DR=128, H=128, DOUT=64
// out[b,n,m,o] = relu( (x_ctx[b,n]-x_ctx[b,m]) @ W1[0:2] + r[b] @ W1[2:130] + b1 ) @ W2 + b2
//
// Round-14: REVERT to exact Round-11 (session best, 32.9us).
// Session conclusion (R1-R13): kernel is write-path-bound at ~4.6 TB/s
// effective -- invariant to store-WAR depth (R9/R10/R13 neutral), writer
// occupancy (R12: 8 waves/CU WORSE than 4), and schedule structure.
// Write floor: 144MiB output / 4.6TB/s ~= 31us + ~2us prologue = ~33us.
// Structure: persistent 1 block/CU (grid 256, 4 waves), 6 rows/block
// (384%6==0 -> rows never span a batch), prologue amortized 6x, per-wave
// LDS transpose (XOR block swizzle) -> 4x1KB fully-contiguous cached
// stores per tile (R6 strided=3.0TB/s, R7 NT=2.1TB/s, R8 asm=RFO blowup).
// MFMA D-layout (m89-verified): col=lane&15, row=(lane>>4)*4+reg.

typedef __attribute__((ext_vector_type(8))) __bf16 bf16x8;
typedef __attribute__((ext_vector_type(4))) float f32x4;

#define B_    4
#define N_    384
#define H_    128
#define DOUT_ 64

__global__ __launch_bounds__(256, 1) void te_fused(
    const float* __restrict__ r, const float* __restrict__ xctx,
    const float* __restrict__ W1, const float* __restrict__ b1,
    const float* __restrict__ W2, const float* __restrict__ b2,
    float* __restrict__ out)
{
    __shared__ __align__(16) float xs[N_ * 2];        // 3 KB  x_ctx[b]
    __shared__ __align__(16) float cpart[2][H_];      // 1 KB  c partials
    __shared__ __align__(16) float tbuf[4][16][64];   // 16 KB per-wave transpose

    const int tid  = threadIdx.x;
    const int wave = tid >> 6, lane = tid & 63;
    const int g = lane >> 4, rl = lane & 15;

    const int bid  = blockIdx.x;       // 0..255
    const int row0 = bid * 6;          // first global row; all 6 share b
    const int b    = row0 / N_;
    const int n0   = row0 - b * N_;

    // ---- prologue: c partial reduction (all 256 threads) ----
    {
        const int k = tid & 127, dh = tid >> 7;
        float acc = dh ? 0.f : b1[k];
        const float* wc = W1 + (2 + dh * 64) * H_ + k;
        const float* rb = r + b * 128 + dh * 64;
        #pragma unroll 8
        for (int d = 0; d < 64; ++d) acc = fmaf(rb[d], wc[d * H_], acc);
        cpart[dh][k] = acc;
    }
    // ---- stage x_ctx[b] (192 threads x 16 B) ----
    if (tid < 192)
        *reinterpret_cast<f32x4*>(&xs[tid * 4]) =
            *reinterpret_cast<const f32x4*>(xctx + b * (N_ * 2) + tid * 4);

    // ---- W2^T fragments: w2f[rt][ks][jj] = bf16(W2[kk][rt*16+rl]),
    //      kk = ks*32 + (jj>=4)*16 + g*4 + (jj&3)  (scalar gathers, L2-hit) ----
    bf16x8 w2f[4][4];
    #pragma unroll
    for (int rt = 0; rt < 4; ++rt) {
        const float* wp = W2 + rt * 16 + rl;   // + kk*64
        #pragma unroll
        for (int ks = 0; ks < 4; ++ks)
            #pragma unroll
            for (int jj = 0; jj < 8; ++jj) {
                const int kk = ks * 32 + ((jj >> 2) << 4) + (g << 2) + (jj & 3);
                w2f[rt][ks][jj] = (__bf16)wp[kk * DOUT_];
            }
    }

    // ---- W1 row-0/row-1 fragments + b2 fragments ----
    f32x4 w1a[4][2], w1b[4][2], cf[4][2], b2f[4];
    #pragma unroll
    for (int ks = 0; ks < 4; ++ks)
        #pragma unroll
        for (int hh = 0; hh < 2; ++hh) {
            const int kk = ks * 32 + hh * 16 + (g << 2);
            w1a[ks][hh] = *reinterpret_cast<const f32x4*>(W1 + kk);
            w1b[ks][hh] = *reinterpret_cast<const f32x4*>(W1 + H_ + kk);
        }
    #pragma unroll
    for (int rt = 0; rt < 4; ++rt)
        b2f[rt] = *reinterpret_cast<const f32x4*>(b2 + rt * 16 + (g << 2));

    __syncthreads();   // xs + cpart ready (only barrier in the kernel)

    // ---- c fragments ----
    #pragma unroll
    for (int ks = 0; ks < 4; ++ks)
        #pragma unroll
        for (int hh = 0; hh < 2; ++hh) {
            const int kk = ks * 32 + hh * 16 + (g << 2);
            cf[ks][hh] = *reinterpret_cast<const f32x4*>(&cpart[0][kk]) +
                         *reinterpret_cast<const f32x4*>(&cpart[1][kk]);
        }

    float* tb = &tbuf[wave][0][0];
    const int cb2 = lane & 15;

    // ---- 6 rows x 6 m-tiles; store pattern identical to R4 ----
    for (int rr = 0; rr < 6; ++rr) {
        const int n = n0 + rr;
        const float x0n = xs[2 * n], x1n = xs[2 * n + 1];
        float* const outn = out + ((size_t)(row0 + rr)) * N_ * DOUT_;

        for (int t = 0; t < 6; ++t) {
            const int mbase = wave * 96 + t * 16;
            const int m = mbase + rl;
            const float dx0 = x0n - xs[2 * m];
            const float dx1 = x1n - xs[2 * m + 1];

            bf16x8 hf[4];
            #pragma unroll
            for (int ks = 0; ks < 4; ++ks)
                #pragma unroll
                for (int hh = 0; hh < 2; ++hh)
                    #pragma unroll
                    for (int j = 0; j < 4; ++j) {
                        float hp = fmaf(dx1, w1b[ks][hh][j],
                                   fmaf(dx0, w1a[ks][hh][j], cf[ks][hh][j]));
                        hf[ks][hh * 4 + j] = (__bf16)(hp > 0.f ? hp : 0.f);
                    }

            f32x4 acc[4];
            #pragma unroll
            for (int rt = 0; rt < 4; ++rt) acc[rt] = b2f[rt];
            #pragma unroll
            for (int ks = 0; ks < 4; ++ks)
                #pragma unroll
                for (int rt = 0; rt < 4; ++rt)
                    acc[rt] = __builtin_amdgcn_mfma_f32_16x16x32_bf16(w2f[rt][ks], hf[ks], acc[rt], 0, 0, 0);

            // per-wave LDS transpose (XOR block swizzle) -> 4 x 1KB contiguous stores
            #pragma unroll
            for (int rt = 0; rt < 4; ++rt) {
                const int cblk = ((rt << 2) | g) ^ rl;
                *reinterpret_cast<f32x4*>(tb + (rl << 6) + (cblk << 2)) = acc[rt];
            }
            float* onp = outn + (size_t)mbase * DOUT_;
            #pragma unroll
            for (int q = 0; q < 4; ++q) {
                const int mm = (lane >> 4) | (q << 2);
                f32x4 rowv = *reinterpret_cast<const f32x4*>(tb + (mm << 6) + ((cb2 ^ mm) << 2));
                *reinterpret_cast<f32x4*>(onp + mm * DOUT_ + (cb2 << 2)) = rowv;
            }
        }
    }
}

extern "C" void kernel_launch(void* const* d_in, const int* in_sizes, int n_in,
                              void* d_out, int out_size, void* d_ws, size_t ws_size,
                              hipStream_t stream)
{
    const float* r    = (const float*)d_in[0];
    const float* xctx = (const float*)d_in[1];
    // d_in[2] = y_ctx (unused), d_in[3] = x_trg (unused)
    const float* W1 = (const float*)d_in[4];
    const float* b1 = (const float*)d_in[5];
    const float* W2 = (const float*)d_in[6];
    const float* b2 = (const float*)d_in[7];
    float* out = (float*)d_out;

    hipLaunchKernelGGL(te_fused, dim3(256), dim3(256), 0, stream,
                       r, xctx, W1, b1, W2, b2, out);
}